// Round 2
// baseline (810.228 us; speedup 1.0000x reference)
//
#include <hip/hip_runtime.h>
#include <hip/hip_cooperative_groups.h>
#include <math.h>

namespace cg = cooperative_groups;

#define N 8192
#define C 10
#define NUM_ITERS 5
#define FBLOCK 256        /* filter block: 4 waves */
#define JCH 8             /* j splits (partial accumulators) */
#define JPB (N / JCH)     /* 1024 j's per block */
#define JT 256            /* j's staged per LDS chunk (trimmed: coop occupancy calc uses 64KB pool) */
#define IBLK 128          /* i's per filter block: 4 waves x 32 */
#define NIB (N / IBLK)    /* 64 */
#define LOG2E 1.44269504088896340736f
#define C3 (LOG2E / 64.0f)
#define PROW (JT + 8)     /* 264: il stride 528B -> il*4 mod 32 banks, 2-way (free) */

typedef _Float16 half8 __attribute__((ext_vector_type(8)));
typedef _Float16 half4 __attribute__((ext_vector_type(4)));
typedef float f32x4 __attribute__((ext_vector_type(4)));

// ws byte offsets:
//   ajs half8[N] : j-side spatial aug features   [f*C3 x3, 0, 0,0,-h3*C3, 1]
//   ajb half8[N] : j-side bilateral aug features [f*L2E x6, -h6*L2E, 1]
//   pf  f16[16][N] : softmax probs, rows 10..15 zero
//   part float[JCH][20][N] : per-j-split partials (reduced inline in combine)
#define WS_AJS 0
#define WS_AJB (N * 16)
#define WS_PF  (N * 32)
#define WS_PART (N * 64)

struct FilterSmem {
    half4 ajs_l[JT * 2];        // 4 KB  [j][h]
    half4 ajb_l[JT * 2];        // 4 KB
    _Float16 p_l[16 * PROW];    // 8.25 KB
};
struct CombineSmem {
    float sSW[100], sBW[100], sCM[100];
    float spl[10][128], bll[10][128], ul[10][128];
};
union SmemU { FilterSmem f; CombineSmem c; };   // 16,640 B -> 3 blocks/CU even vs 64KB pool

static __device__ __forceinline__ half4 expcvt(f32x4 d) {
    half4 r;
    r[0] = (_Float16)__builtin_amdgcn_exp2f(d[0]);
    r[1] = (_Float16)__builtin_amdgcn_exp2f(d[1]);
    r[2] = (_Float16)__builtin_amdgcn_exp2f(d[2]);
    r[3] = (_Float16)__builtin_amdgcn_exp2f(d[3]);
    return r;
}

// ---------------- shared device bodies (used by BOTH coop and fallback paths) ----------------

static __device__ __forceinline__ void init_body(
    int n, const float* __restrict__ unaries, const float* __restrict__ feat,
    half8* __restrict__ ajs8, half8* __restrict__ ajb8, _Float16* __restrict__ pf) {
    float f6[6];
#pragma unroll
    for (int d = 0; d < 6; ++d) f6[d] = feat[d * N + n];
    float h3 = 0.5f * (f6[0] * f6[0] + f6[1] * f6[1] + f6[2] * f6[2]);
    float h6v = h3 + 0.5f * (f6[3] * f6[3] + f6[4] * f6[4] + f6[5] * f6[5]);
    half8 a = {};
    a[0] = (_Float16)(f6[0] * C3);
    a[1] = (_Float16)(f6[1] * C3);
    a[2] = (_Float16)(f6[2] * C3);
    a[6] = (_Float16)(-h3 * C3);
    a[7] = (_Float16)1.0f;
    ajs8[n] = a;
    half8 b;
#pragma unroll
    for (int d = 0; d < 6; ++d) b[d] = (_Float16)(f6[d] * LOG2E);
    b[6] = (_Float16)(-h6v * LOG2E);
    b[7] = (_Float16)1.0f;
    ajb8[n] = b;

    float q[C];
#pragma unroll
    for (int c = 0; c < C; ++c) q[c] = unaries[c * N + n];
    float m = q[0];
#pragma unroll
    for (int c = 1; c < C; ++c) m = fmaxf(m, q[c]);
    float e[C], s = 0.0f;
#pragma unroll
    for (int c = 0; c < C; ++c) {
        e[c] = __builtin_amdgcn_exp2f((q[c] - m) * LOG2E);
        s += e[c];
    }
    float inv = 1.0f / s;
#pragma unroll
    for (int c = 0; c < C; ++c) pf[c * N + n] = (_Float16)(e[c] * inv);
#pragma unroll
    for (int c = C; c < 16; ++c) pf[c * N + n] = (_Float16)0.0f;
}

static __device__ __forceinline__ void compute_b1(
    const float* __restrict__ feat, int i0, int il, int h, bool klo,
    half4& b1s0, half4& b1s1, half4& b1b0, half4& b1b1) {
    const half4 hz = {};
#pragma unroll
    for (int s = 0; s < 2; ++s) {
        int i = i0 + s * 16 + il;
        float g0 = feat[0 * N + i], g1 = feat[1 * N + i], g2 = feat[2 * N + i];
        float g3 = feat[3 * N + i], g4 = feat[4 * N + i], g5 = feat[5 * N + i];
        float h3 = 0.5f * (g0 * g0 + g1 * g1 + g2 * g2);
        float h6v = h3 + 0.5f * (g3 * g3 + g4 * g4 + g5 * g5);
        half4 slo = {(_Float16)g0, (_Float16)g1, (_Float16)g2, (_Float16)0.0f};
        half4 shi = {(_Float16)0.0f, (_Float16)0.0f, (_Float16)1.0f, (_Float16)(-h3 * C3)};
        half4 blo = {(_Float16)g0, (_Float16)g1, (_Float16)g2, (_Float16)g3};
        half4 bhi = {(_Float16)g4, (_Float16)g5, (_Float16)1.0f, (_Float16)(-h6v * LOG2E)};
        half4 vs = klo ? (h ? shi : slo) : hz;
        half4 vb = klo ? (h ? bhi : blo) : hz;
        if (s == 0) { b1s0 = vs; b1b0 = vb; } else { b1s1 = vs; b1b1 = vb; }
    }
}

static __device__ __forceinline__ void filter_body(
    FilterSmem* sm, int t, int ib, int jc,
    const half4* __restrict__ ajs, const half4* __restrict__ ajb,
    const _Float16* __restrict__ pf, float* __restrict__ part,
    half4 b1s0, half4 b1s1, half4 b1b0, half4 b1b1) {
    int lane = t & 63;
    int w = t >> 6;
    int il = lane & 15;
    int quad = lane >> 4;
    int h = quad & 1;
    bool klo = (quad < 2);
    int i0 = ib * IBLK + w * 32;
    const half4 hz = {};

    f32x4 as0 = {0.f, 0.f, 0.f, 0.f}, as1 = {0.f, 0.f, 0.f, 0.f};
    f32x4 ab0 = {0.f, 0.f, 0.f, 0.f}, ab1 = {0.f, 0.f, 0.f, 0.f};
    const f32x4 zero = {0.f, 0.f, 0.f, 0.f};

    for (int ch = 0; ch < JPB / JT; ++ch) {
        int jbase = jc * JPB + ch * JT;
        {
            const float4* s0 = (const float4*)(ajs + (size_t)jbase * 2);
            const float4* s1 = (const float4*)(ajb + (size_t)jbase * 2);
            float4* d0 = (float4*)sm->ajs_l;
            float4* d1 = (float4*)sm->ajb_l;
            for (int k = t; k < JT; k += FBLOCK) { d0[k] = s0[k]; d1[k] = s1[k]; }
            const float4* ps = (const float4*)pf;
            float4* pd = (float4*)sm->p_l;
            for (int k = t; k < 16 * (JT / 8); k += FBLOCK) {
                int c = k >> 5, off = k & 31;      // JT=256: 32 float4 per row
                pd[c * (PROW / 8) + off] = ps[c * (N / 8) + (jbase >> 3) + off];
            }
        }
        __syncthreads();

#pragma unroll 2
        for (int jb = 0; jb < JT; jb += 32) {
            int j0 = jb, j1 = jb + 16;
            half4 vs0 = sm->ajs_l[(j0 + il) * 2 + h];
            half4 vb0 = sm->ajb_l[(j0 + il) * 2 + h];
            half4 vs1 = sm->ajs_l[(j1 + il) * 2 + h];
            half4 vb1 = sm->ajb_l[(j1 + il) * 2 + h];
            half4 p2_0 = *(const half4*)&sm->p_l[il * PROW + j0 + quad * 4];
            half4 p2_1 = *(const half4*)&sm->p_l[il * PROW + j1 + quad * 4];
            half4 a1s_0 = klo ? vs0 : hz;
            half4 a1b_0 = klo ? vb0 : hz;
            half4 a1s_1 = klo ? vs1 : hz;
            half4 a1b_1 = klo ? vb1 : hz;

            // GEMM-1: S^T[j][i] in C/D layout (8 independent chains)
            f32x4 d0 = __builtin_amdgcn_mfma_f32_16x16x16f16(a1s_0, b1s0, zero, 0, 0, 0);
            f32x4 d1 = __builtin_amdgcn_mfma_f32_16x16x16f16(a1s_0, b1s1, zero, 0, 0, 0);
            f32x4 d2 = __builtin_amdgcn_mfma_f32_16x16x16f16(a1b_0, b1b0, zero, 0, 0, 0);
            f32x4 d3 = __builtin_amdgcn_mfma_f32_16x16x16f16(a1b_0, b1b1, zero, 0, 0, 0);
            f32x4 d4 = __builtin_amdgcn_mfma_f32_16x16x16f16(a1s_1, b1s0, zero, 0, 0, 0);
            f32x4 d5 = __builtin_amdgcn_mfma_f32_16x16x16f16(a1s_1, b1s1, zero, 0, 0, 0);
            f32x4 d6 = __builtin_amdgcn_mfma_f32_16x16x16f16(a1b_1, b1b0, zero, 0, 0, 0);
            f32x4 d7 = __builtin_amdgcn_mfma_f32_16x16x16f16(a1b_1, b1b1, zero, 0, 0, 0);

            half4 w0 = expcvt(d0), w1 = expcvt(d1), w2 = expcvt(d2), w3 = expcvt(d3);
            half4 w4 = expcvt(d4), w5 = expcvt(d5), w6 = expcvt(d6), w7 = expcvt(d7);

            // GEMM-2: out[i][c] += w[i][j] * p[c][j]
            as0 = __builtin_amdgcn_mfma_f32_16x16x16f16(w0, p2_0, as0, 0, 0, 0);
            as1 = __builtin_amdgcn_mfma_f32_16x16x16f16(w1, p2_0, as1, 0, 0, 0);
            ab0 = __builtin_amdgcn_mfma_f32_16x16x16f16(w2, p2_0, ab0, 0, 0, 0);
            ab1 = __builtin_amdgcn_mfma_f32_16x16x16f16(w3, p2_0, ab1, 0, 0, 0);
            as0 = __builtin_amdgcn_mfma_f32_16x16x16f16(w4, p2_1, as0, 0, 0, 0);
            as1 = __builtin_amdgcn_mfma_f32_16x16x16f16(w5, p2_1, as1, 0, 0, 0);
            ab0 = __builtin_amdgcn_mfma_f32_16x16x16f16(w6, p2_1, ab0, 0, 0, 0);
            ab1 = __builtin_amdgcn_mfma_f32_16x16x16f16(w7, p2_1, ab1, 0, 0, 0);
        }
        __syncthreads();
    }

    if (il < C) {
        float* psp = part + ((size_t)jc * 20 + il) * N;
        float* pbl = part + ((size_t)jc * 20 + C + il) * N;
        int ia = i0 + quad * 4;
#pragma unroll
        for (int r = 0; r < 4; ++r) {
            psp[ia + r]      = as0[r];
            psp[ia + 16 + r] = as1[r];
            pbl[ia + r]      = ab0[r];
            pbl[ia + 16 + r] = ab1[r];
        }
    }
}

static __device__ __forceinline__ void combine_body(
    CombineSmem* smc, int t, int bid,
    const float* __restrict__ unaries, const float* __restrict__ SW,
    const float* __restrict__ BW, const float* __restrict__ CM,
    const float* __restrict__ part, _Float16* __restrict__ pf,
    float* __restrict__ out, int is_last) {
    if (t < 100) { smc->sSW[t] = SW[t]; smc->sBW[t] = BW[t]; smc->sCM[t] = CM[t]; }
    int nl = t & 127;
    int hh = t >> 7;
    int n = bid * 128 + nl;

    if (hh == 0) {
#pragma unroll
        for (int k = 0; k < C; ++k) {
            float s = 0.0f;
#pragma unroll
            for (int jcc = 0; jcc < JCH; ++jcc)
                s += part[((size_t)jcc * 20 + k) * N + n];
            smc->spl[k][nl] = s;
        }
#pragma unroll
        for (int k = 0; k < 5; ++k) smc->ul[k][nl] = unaries[k * N + n];
    } else {
#pragma unroll
        for (int k = 0; k < C; ++k) {
            float s = 0.0f;
#pragma unroll
            for (int jcc = 0; jcc < JCH; ++jcc)
                s += part[((size_t)jcc * 20 + C + k) * N + n];
            smc->bll[k][nl] = s;
        }
#pragma unroll
        for (int k = 5; k < C; ++k) smc->ul[k][nl] = unaries[k * N + n];
    }
    __syncthreads();

    float q[C];
#pragma unroll
    for (int c = 0; c < C; ++c) {
        float m = 0.0f;
#pragma unroll
        for (int k = 0; k < C; ++k)
            m += smc->sSW[c * C + k] * smc->spl[k][nl] +
                 smc->sBW[c * C + k] * smc->bll[k][nl];
        q[c] = m;   // msg
    }
    float qq[C];
#pragma unroll
    for (int c = 0; c < C; ++c) {
        float pw = 0.0f;
#pragma unroll
        for (int k = 0; k < C; ++k) pw += smc->sCM[c * C + k] * q[k];
        qq[c] = smc->ul[c][nl] - pw;
    }

    if (is_last) {
#pragma unroll
        for (int c = 0; c < 5; ++c) out[(hh * 5 + c) * N + n] = qq[hh * 5 + c];
    } else {
        float m = qq[0];
#pragma unroll
        for (int c = 1; c < C; ++c) m = fmaxf(m, qq[c]);
        float e[C], s = 0.0f;
#pragma unroll
        for (int c = 0; c < C; ++c) {
            e[c] = __builtin_amdgcn_exp2f((qq[c] - m) * LOG2E);
            s += e[c];
        }
        float inv = 1.0f / s;
#pragma unroll
        for (int c = 0; c < 8; ++c) {
            int row = hh * 8 + c;
            float v = (row < C) ? e[row] * inv : 0.0f;
            pf[row * N + n] = (_Float16)v;
        }
    }
}

// ---------------- cooperative mega-kernel ----------------

__global__ __launch_bounds__(FBLOCK, 2) void crf_coop(
    const float* __restrict__ unaries, const float* __restrict__ feat,
    const float* __restrict__ SW, const float* __restrict__ BW,
    const float* __restrict__ CM, half8* __restrict__ ajs8,
    half8* __restrict__ ajb8, _Float16* __restrict__ pf,
    float* __restrict__ part, float* __restrict__ out) {
    cg::grid_group grid = cg::this_grid();
    __shared__ SmemU sm;

    int t = threadIdx.x;
    int bid = blockIdx.x;
    const half4* ajs = (const half4*)ajs8;
    const half4* ajb = (const half4*)ajb8;

    if (bid < N / 256) init_body(bid * 256 + t, unaries, feat, ajs8, ajb8, pf);

    int lane = t & 63;
    int w = t >> 6;
    int il = lane & 15;
    int quad = lane >> 4;
    int h = quad & 1;
    bool klo = (quad < 2);
    int ib = bid & (NIB - 1);
    int jc = bid >> 6;
    int i0 = ib * IBLK + w * 32;

    half4 b1s0, b1s1, b1b0, b1b1;
    compute_b1(feat, i0, il, h, klo, b1s0, b1s1, b1b0, b1b1);

    grid.sync();

    for (int it = 1; it <= NUM_ITERS; ++it) {
        filter_body(&sm.f, t, ib, jc, ajs, ajb, pf, part, b1s0, b1s1, b1b0, b1b1);
        grid.sync();
        if (bid < N / 128)
            combine_body(&sm.c, t, bid, unaries, SW, BW, CM, part, pf, out,
                         it == NUM_ITERS ? 1 : 0);
        if (it < NUM_ITERS) grid.sync();
    }
}

// ---------------- fallback multi-kernel path (known-correct structure) ----------------

__global__ __launch_bounds__(256) void init_kernel(
    const float* __restrict__ unaries, const float* __restrict__ feat,
    half8* __restrict__ ajs, half8* __restrict__ ajb, _Float16* __restrict__ pf) {
    init_body(blockIdx.x * 256 + threadIdx.x, unaries, feat, ajs, ajb, pf);
}

__global__ __launch_bounds__(FBLOCK, 2) void filter_kernel(
    const float* __restrict__ feat, const half4* __restrict__ ajs,
    const half4* __restrict__ ajb, const _Float16* __restrict__ pf,
    float* __restrict__ part) {
    __shared__ FilterSmem sm;
    int t = threadIdx.x;
    int ib = blockIdx.x;
    int jc = blockIdx.y;
    int lane = t & 63;
    int w = t >> 6;
    int il = lane & 15;
    int quad = lane >> 4;
    int h = quad & 1;
    bool klo = (quad < 2);
    int i0 = ib * IBLK + w * 32;
    half4 b1s0, b1s1, b1b0, b1b1;
    compute_b1(feat, i0, il, h, klo, b1s0, b1s1, b1b0, b1b1);
    filter_body(&sm, t, ib, jc, ajs, ajb, pf, part, b1s0, b1s1, b1b0, b1b1);
}

__global__ __launch_bounds__(256) void combine_kernel(
    const float* __restrict__ unaries, const float* __restrict__ SW,
    const float* __restrict__ BW, const float* __restrict__ CM,
    const float* __restrict__ part, _Float16* __restrict__ pf,
    float* __restrict__ out, int is_last) {
    __shared__ CombineSmem sm;
    combine_body(&sm, threadIdx.x, blockIdx.x, unaries, SW, BW, CM, part, pf, out,
                 is_last);
}

extern "C" void kernel_launch(void* const* d_in, const int* in_sizes, int n_in,
                              void* d_out, int out_size, void* d_ws, size_t ws_size,
                              hipStream_t stream) {
    const float* unaries = (const float*)d_in[0];   // [10, 8192]
    const float* feat    = (const float*)d_in[1];   // [6, 8192]
    const float* SW      = (const float*)d_in[2];   // [10,10]
    const float* BW      = (const float*)d_in[3];   // [10,10]
    const float* CM      = (const float*)d_in[4];   // [10,10]
    float* out = (float*)d_out;

    char* ws = (char*)d_ws;
    half8* ajs    = (half8*)(ws + WS_AJS);
    half8* ajb    = (half8*)(ws + WS_AJB);
    _Float16* pf  = (_Float16*)(ws + WS_PF);
    float* part   = (float*)(ws + WS_PART);

    void* args[] = {(void*)&unaries, (void*)&feat, (void*)&SW, (void*)&BW, (void*)&CM,
                    (void*)&ajs, (void*)&ajb, (void*)&pf, (void*)&part, (void*)&out};
    hipError_t rc = hipLaunchCooperativeKernel((const void*)crf_coop, dim3(NIB * JCH),
                                               dim3(FBLOCK), args, 0, stream);
    if (rc != hipSuccess) {
        (void)hipGetLastError();   // clear sticky error from the failed launch
        init_kernel<<<N / 256, 256, 0, stream>>>(unaries, feat, ajs, ajb, pf);
        for (int it = 1; it <= NUM_ITERS; ++it) {
            filter_kernel<<<dim3(NIB, JCH), FBLOCK, 0, stream>>>(
                feat, (const half4*)ajs, (const half4*)ajb, pf, part);
            combine_kernel<<<N / 128, 256, 0, stream>>>(unaries, SW, BW, CM, part, pf,
                                                        out, it == NUM_ITERS ? 1 : 0);
        }
    }
}

// Round 3
// 195.903 us; speedup vs baseline: 4.1359x; 4.1359x over previous
//
#include <hip/hip_runtime.h>
#include <math.h>

#define N 8192
#define C 10
#define NUM_ITERS 5
#define FBLOCK 512         /* 8 waves per block */
#define JT 512             /* j's staged per LDS window */
#define NWIN (N / JT)      /* 16 windows per iteration */
#define IBLK 32            /* i's per block */
#define NBLK (N / IBLK)    /* 256 blocks = 1 per CU */
#define LOG2E 1.44269504088896340736f
#define C3 (LOG2E / 64.0f)
#define PROW (JT + 8)      /* 520: padded LDS row for p (f16 elems) */

typedef _Float16 half8 __attribute__((ext_vector_type(8)));
typedef _Float16 half4 __attribute__((ext_vector_type(4)));
typedef float f32x4 __attribute__((ext_vector_type(4)));

// ws layout:
//   ajs half8[N]  : j-side spatial aug features   [f*C3 x3, 0, 0,0,-h3*C3, 1]
//   ajb half8[N]  : j-side bilateral aug features [f*L2E x6, -h6*L2E, 1]
//   pf0 f16[16][N]: softmax probs (ping)  rows 10..15 zero
//   pf1 f16[16][N]: softmax probs (pong)  rows 10..15 zero
#define WS_AJS 0
#define WS_AJB (N * 16)
#define WS_PF0 (N * 32)
#define WS_PF1 (N * 64)

struct FilterSmem {
    half4 ajs_l[JT * 2];        //  8 KB  [j][h]
    half4 ajb_l[JT * 2];        //  8 KB
    _Float16 p_l[16 * PROW];    // 16.25 KB
};
union FusedSmem {
    FilterSmem f;
    float rbuf[8 * 1024];       // 32 KB: per-wave accumulator dump for reduction
};

static __device__ __forceinline__ half4 expcvt(f32x4 d) {
    half4 r;
    r[0] = (_Float16)__builtin_amdgcn_exp2f(d[0]);
    r[1] = (_Float16)__builtin_amdgcn_exp2f(d[1]);
    r[2] = (_Float16)__builtin_amdgcn_exp2f(d[2]);
    r[3] = (_Float16)__builtin_amdgcn_exp2f(d[3]);
    return r;
}

// once per launch: aug features + softmax(unaries) -> pf0; zero rows 10..15 of both pf
__global__ __launch_bounds__(256) void init_kernel(
    const float* __restrict__ unaries, const float* __restrict__ feat,
    half8* __restrict__ ajs8, half8* __restrict__ ajb8,
    _Float16* __restrict__ pf0, _Float16* __restrict__ pf1) {
    int n = blockIdx.x * 256 + threadIdx.x;
    float f6[6];
#pragma unroll
    for (int d = 0; d < 6; ++d) f6[d] = feat[d * N + n];
    float h3 = 0.5f * (f6[0] * f6[0] + f6[1] * f6[1] + f6[2] * f6[2]);
    float h6v = h3 + 0.5f * (f6[3] * f6[3] + f6[4] * f6[4] + f6[5] * f6[5]);
    half8 a = {};
    a[0] = (_Float16)(f6[0] * C3);
    a[1] = (_Float16)(f6[1] * C3);
    a[2] = (_Float16)(f6[2] * C3);
    a[6] = (_Float16)(-h3 * C3);
    a[7] = (_Float16)1.0f;
    ajs8[n] = a;
    half8 b;
#pragma unroll
    for (int d = 0; d < 6; ++d) b[d] = (_Float16)(f6[d] * LOG2E);
    b[6] = (_Float16)(-h6v * LOG2E);
    b[7] = (_Float16)1.0f;
    ajb8[n] = b;

    float q[C];
#pragma unroll
    for (int c = 0; c < C; ++c) q[c] = unaries[c * N + n];
    float m = q[0];
#pragma unroll
    for (int c = 1; c < C; ++c) m = fmaxf(m, q[c]);
    float e[C], s = 0.0f;
#pragma unroll
    for (int c = 0; c < C; ++c) {
        e[c] = __builtin_amdgcn_exp2f((q[c] - m) * LOG2E);
        s += e[c];
    }
    float inv = 1.0f / s;
#pragma unroll
    for (int c = 0; c < C; ++c) pf0[c * N + n] = (_Float16)(e[c] * inv);
#pragma unroll
    for (int c = C; c < 16; ++c) {
        pf0[c * N + n] = (_Float16)0.0f;
        pf1[c * N + n] = (_Float16)0.0f;
    }
}

// one dispatch per CRF iteration: block owns 32 i's; 8 waves sweep all N j's
// (each wave takes 64 j's of every 512-j window); LDS-reduce across waves;
// combine + softmax in-block. pf double-buffered across dispatches.
__global__ __launch_bounds__(FBLOCK, 2) void fused_kernel(
    const float* __restrict__ unaries, const float* __restrict__ feat,
    const float* __restrict__ SW, const float* __restrict__ BW,
    const float* __restrict__ CM,
    const float4* __restrict__ ajsv, const float4* __restrict__ ajbv,
    const _Float16* __restrict__ pf_in, _Float16* __restrict__ pf_out,
    float* __restrict__ out, int is_last) {
    __shared__ FusedSmem sm;
    int t = threadIdx.x;
    int i0 = blockIdx.x * IBLK;
    int lane = t & 63;
    int w = t >> 6;
    int il = lane & 15;
    int quad = lane >> 4;
    int h = quad & 1;
    bool klo = (quad < 2);
    const half4 hz = {};

    // ---- i-side B1 fragments (32 i's, 2 subtiles of 16) ----
    half4 b1s0, b1s1, b1b0, b1b1;
#pragma unroll
    for (int s = 0; s < 2; ++s) {
        int i = i0 + s * 16 + il;
        float g0 = feat[0 * N + i], g1 = feat[1 * N + i], g2 = feat[2 * N + i];
        float g3 = feat[3 * N + i], g4 = feat[4 * N + i], g5 = feat[5 * N + i];
        float h3 = 0.5f * (g0 * g0 + g1 * g1 + g2 * g2);
        float h6v = h3 + 0.5f * (g3 * g3 + g4 * g4 + g5 * g5);
        half4 slo = {(_Float16)g0, (_Float16)g1, (_Float16)g2, (_Float16)0.0f};
        half4 shi = {(_Float16)0.0f, (_Float16)0.0f, (_Float16)1.0f, (_Float16)(-h3 * C3)};
        half4 blo = {(_Float16)g0, (_Float16)g1, (_Float16)g2, (_Float16)g3};
        half4 bhi = {(_Float16)g4, (_Float16)g5, (_Float16)1.0f, (_Float16)(-h6v * LOG2E)};
        half4 vs = klo ? (h ? shi : slo) : hz;
        half4 vb = klo ? (h ? bhi : blo) : hz;
        if (s == 0) { b1s0 = vs; b1b0 = vb; } else { b1s1 = vs; b1b1 = vb; }
    }

    f32x4 as0 = {0.f, 0.f, 0.f, 0.f}, as1 = {0.f, 0.f, 0.f, 0.f};
    f32x4 ab0 = {0.f, 0.f, 0.f, 0.f}, ab1 = {0.f, 0.f, 0.f, 0.f};
    const f32x4 zero = {0.f, 0.f, 0.f, 0.f};

    const float4* ps = (const float4*)pf_in;
    int c0 = t >> 6, o0 = t & 63;            // p-staging: row c0 (0..7), offset o0
    int c1 = c0 + 8;                          // second half: rows 8..15

    // ---- prologue: load window 0 into registers (T14 issue-early) ----
    float4 r_s = ajsv[t];
    float4 r_b = ajbv[t];
    float4 r_p0 = ps[c0 * (N / 8) + o0];
    float4 r_p1 = ps[c1 * (N / 8) + o0];

    for (int win = 0; win < NWIN; ++win) {
        // write staged registers to LDS
        {
            float4* d0 = (float4*)sm.f.ajs_l;
            float4* d1 = (float4*)sm.f.ajb_l;
            float4* pd = (float4*)sm.f.p_l;
            d0[t] = r_s;
            d1[t] = r_b;
            pd[c0 * (PROW / 8) + o0] = r_p0;
            pd[c1 * (PROW / 8) + o0] = r_p1;
        }
        __syncthreads();
        // issue next window's global loads (latency hides under compute)
        if (win + 1 < NWIN) {
            int jb2 = (win + 1) * JT;
            r_s = ajsv[jb2 + t];
            r_b = ajbv[jb2 + t];
            r_p0 = ps[c0 * (N / 8) + (jb2 >> 3) + o0];
            r_p1 = ps[c1 * (N / 8) + (jb2 >> 3) + o0];
        }
        // compute: wave w handles j in [w*64, w*64+64) of this window
#pragma unroll
        for (int s = 0; s < 2; ++s) {
            int jb = w * 64 + s * 32;
            int j0 = jb, j1 = jb + 16;
            half4 vs0 = sm.f.ajs_l[(j0 + il) * 2 + h];
            half4 vb0 = sm.f.ajb_l[(j0 + il) * 2 + h];
            half4 vs1 = sm.f.ajs_l[(j1 + il) * 2 + h];
            half4 vb1 = sm.f.ajb_l[(j1 + il) * 2 + h];
            half4 p2_0 = *(const half4*)&sm.f.p_l[il * PROW + j0 + quad * 4];
            half4 p2_1 = *(const half4*)&sm.f.p_l[il * PROW + j1 + quad * 4];
            half4 a1s_0 = klo ? vs0 : hz;
            half4 a1b_0 = klo ? vb0 : hz;
            half4 a1s_1 = klo ? vs1 : hz;
            half4 a1b_1 = klo ? vb1 : hz;

            // GEMM-1: S^T[j][i] in C/D layout (8 independent chains)
            f32x4 d0 = __builtin_amdgcn_mfma_f32_16x16x16f16(a1s_0, b1s0, zero, 0, 0, 0);
            f32x4 d1 = __builtin_amdgcn_mfma_f32_16x16x16f16(a1s_0, b1s1, zero, 0, 0, 0);
            f32x4 d2 = __builtin_amdgcn_mfma_f32_16x16x16f16(a1b_0, b1b0, zero, 0, 0, 0);
            f32x4 d3 = __builtin_amdgcn_mfma_f32_16x16x16f16(a1b_0, b1b1, zero, 0, 0, 0);
            f32x4 d4 = __builtin_amdgcn_mfma_f32_16x16x16f16(a1s_1, b1s0, zero, 0, 0, 0);
            f32x4 d5 = __builtin_amdgcn_mfma_f32_16x16x16f16(a1s_1, b1s1, zero, 0, 0, 0);
            f32x4 d6 = __builtin_amdgcn_mfma_f32_16x16x16f16(a1b_1, b1b0, zero, 0, 0, 0);
            f32x4 d7 = __builtin_amdgcn_mfma_f32_16x16x16f16(a1b_1, b1b1, zero, 0, 0, 0);

            half4 w0 = expcvt(d0), w1 = expcvt(d1), w2 = expcvt(d2), w3 = expcvt(d3);
            half4 w4 = expcvt(d4), w5 = expcvt(d5), w6 = expcvt(d6), w7 = expcvt(d7);

            // GEMM-2: out[i][c] += w[i][j] * p[c][j]
            as0 = __builtin_amdgcn_mfma_f32_16x16x16f16(w0, p2_0, as0, 0, 0, 0);
            as1 = __builtin_amdgcn_mfma_f32_16x16x16f16(w1, p2_0, as1, 0, 0, 0);
            ab0 = __builtin_amdgcn_mfma_f32_16x16x16f16(w2, p2_0, ab0, 0, 0, 0);
            ab1 = __builtin_amdgcn_mfma_f32_16x16x16f16(w3, p2_0, ab1, 0, 0, 0);
            as0 = __builtin_amdgcn_mfma_f32_16x16x16f16(w4, p2_1, as0, 0, 0, 0);
            as1 = __builtin_amdgcn_mfma_f32_16x16x16f16(w5, p2_1, as1, 0, 0, 0);
            ab0 = __builtin_amdgcn_mfma_f32_16x16x16f16(w6, p2_1, ab0, 0, 0, 0);
            ab1 = __builtin_amdgcn_mfma_f32_16x16x16f16(w7, p2_1, ab1, 0, 0, 0);
        }
        __syncthreads();
    }

    // ---- cross-wave reduction in LDS (overlays FilterSmem; LDS free after last sync) ----
    {
        float* rb = sm.rbuf + (w * 1024 + lane * 16);
#pragma unroll
        for (int r = 0; r < 4; ++r) {
            rb[r] = as0[r];
            rb[4 + r] = as1[r];
            rb[8 + r] = ab0[r];
            rb[12 + r] = ab1[r];
        }
    }
    __syncthreads();
    {
        float tot0 = 0.f, tot1 = 0.f;
#pragma unroll
        for (int w2 = 0; w2 < 8; ++w2) {
            tot0 += sm.rbuf[w2 * 1024 + t];
            tot1 += sm.rbuf[w2 * 1024 + 512 + t];
        }
        // in-place: position q is only ever read/written by its owning thread
        sm.rbuf[t] = tot0;
        sm.rbuf[512 + t] = tot1;
    }
    __syncthreads();

    // ---- combine + compatibility + softmax for this block's 32 i's ----
    if (t < IBLK) {
        int i = i0 + t;
        int sub = t >> 4, ql = (t & 15) >> 2, rr = t & 3;
        float sp[C], bl[C];
#pragma unroll
        for (int c = 0; c < C; ++c) {
            int base = (ql * 16 + c) * 16 + sub * 4 + rr;
            sp[c] = sm.rbuf[base];
            bl[c] = sm.rbuf[base + 8];
        }
        float msg[C];
#pragma unroll
        for (int c = 0; c < C; ++c) {
            float m = 0.f;
#pragma unroll
            for (int k = 0; k < C; ++k)
                m += SW[c * C + k] * sp[k] + BW[c * C + k] * bl[k];
            msg[c] = m;
        }
        float qq[C];
#pragma unroll
        for (int c = 0; c < C; ++c) {
            float pw = 0.f;
#pragma unroll
            for (int k = 0; k < C; ++k) pw += CM[c * C + k] * msg[k];
            qq[c] = unaries[c * N + i] - pw;
        }
        if (is_last) {
#pragma unroll
            for (int c = 0; c < C; ++c) out[c * N + i] = qq[c];
        } else {
            float m = qq[0];
#pragma unroll
            for (int c = 1; c < C; ++c) m = fmaxf(m, qq[c]);
            float e[C], s = 0.0f;
#pragma unroll
            for (int c = 0; c < C; ++c) {
                e[c] = __builtin_amdgcn_exp2f((qq[c] - m) * LOG2E);
                s += e[c];
            }
            float inv = 1.0f / s;
#pragma unroll
            for (int c = 0; c < C; ++c) pf_out[c * N + i] = (_Float16)(e[c] * inv);
        }
    }
}

extern "C" void kernel_launch(void* const* d_in, const int* in_sizes, int n_in,
                              void* d_out, int out_size, void* d_ws, size_t ws_size,
                              hipStream_t stream) {
    const float* unaries = (const float*)d_in[0];   // [10, 8192]
    const float* feat    = (const float*)d_in[1];   // [6, 8192]
    const float* SW      = (const float*)d_in[2];   // [10,10]
    const float* BW      = (const float*)d_in[3];   // [10,10]
    const float* CM      = (const float*)d_in[4];   // [10,10]
    float* out = (float*)d_out;

    char* ws = (char*)d_ws;
    half8* ajs    = (half8*)(ws + WS_AJS);
    half8* ajb    = (half8*)(ws + WS_AJB);
    _Float16* pf0 = (_Float16*)(ws + WS_PF0);
    _Float16* pf1 = (_Float16*)(ws + WS_PF1);

    init_kernel<<<N / 256, 256, 0, stream>>>(unaries, feat, ajs, ajb, pf0, pf1);
    const _Float16* pin = pf0;
    _Float16* pout = pf1;
    for (int it = 1; it <= NUM_ITERS; ++it) {
        fused_kernel<<<NBLK, FBLOCK, 0, stream>>>(
            unaries, feat, SW, BW, CM, (const float4*)ajs, (const float4*)ajb,
            pin, pout, out, it == NUM_ITERS ? 1 : 0);
        const _Float16* tmp = pout;
        pout = (_Float16*)pin;
        pin = tmp;
    }
}

// Round 4
// 167.474 us; speedup vs baseline: 4.8379x; 1.1698x over previous
//
#include <hip/hip_runtime.h>
#include <math.h>

#define N 8192
#define C 10
#define NUM_ITERS 5
#define FBLOCK 1024        /* 16 waves per block, 1 block/CU, 4 waves/SIMD */
#define JT 1024            /* j's staged per LDS window */
#define NWIN (N / JT)      /* 8 windows per iteration */
#define IBLK 32            /* i's per block */
#define NBLK (N / IBLK)    /* 256 blocks = 1 per CU */
#define LOG2E 1.44269504088896340736f
#define C3 (LOG2E / 64.0f)
#define PROW (JT + 8)      /* 1032: il row stride 2064B -> il*4 banks, 2-way (free) */

typedef _Float16 half8 __attribute__((ext_vector_type(8)));
typedef _Float16 half4 __attribute__((ext_vector_type(4)));
typedef float f32x4 __attribute__((ext_vector_type(4)));

// ws layout:
//   ajs half8[N]  : j-side spatial aug features   [f*C3 x3, 0, 0,0,-h3*C3, 1]
//   ajb half8[N]  : j-side bilateral aug features [f*L2E x6, -h6*L2E, 1]
//   pf0 f16[16][N]: softmax probs (ping)  rows 10..15 zero
//   pf1 f16[16][N]: softmax probs (pong)  rows 10..15 zero
#define WS_AJS 0
#define WS_AJB (N * 16)
#define WS_PF0 (N * 32)
#define WS_PF1 (N * 64)

struct FilterSmem {
    half4 ajs_l[JT * 2];        // 16 KB  [j][h]
    half4 ajb_l[JT * 2];        // 16 KB
    _Float16 p_l[16 * PROW];    // 33 KB
};
union FusedSmem {
    FilterSmem f[2];            // 131.6 KB double-buffered windows
    float rbuf[16 * 1024];      // 64 KB: per-wave accumulator dump for reduction
};

static __device__ __forceinline__ half4 expcvt(f32x4 d) {
    half4 r;
    r[0] = (_Float16)__builtin_amdgcn_exp2f(d[0]);
    r[1] = (_Float16)__builtin_amdgcn_exp2f(d[1]);
    r[2] = (_Float16)__builtin_amdgcn_exp2f(d[2]);
    r[3] = (_Float16)__builtin_amdgcn_exp2f(d[3]);
    return r;
}

static __device__ __forceinline__ void stage_write(
    FilterSmem* fb, int t, int c0, int o0,
    float4 r_s, float4 r_b, float4 r_p0, float4 r_p1) {
    ((float4*)fb->ajs_l)[t] = r_s;
    ((float4*)fb->ajb_l)[t] = r_b;
    float4* pd = (float4*)fb->p_l;
    pd[c0 * (PROW / 8) + o0] = r_p0;
    pd[c0 * (PROW / 8) + 64 + o0] = r_p1;
}

// once per launch: aug features + softmax(unaries) -> pf0; zero rows 10..15 of both pf
__global__ __launch_bounds__(256) void init_kernel(
    const float* __restrict__ unaries, const float* __restrict__ feat,
    half8* __restrict__ ajs8, half8* __restrict__ ajb8,
    _Float16* __restrict__ pf0, _Float16* __restrict__ pf1) {
    int n = blockIdx.x * 256 + threadIdx.x;
    float f6[6];
#pragma unroll
    for (int d = 0; d < 6; ++d) f6[d] = feat[d * N + n];
    float h3 = 0.5f * (f6[0] * f6[0] + f6[1] * f6[1] + f6[2] * f6[2]);
    float h6v = h3 + 0.5f * (f6[3] * f6[3] + f6[4] * f6[4] + f6[5] * f6[5]);
    half8 a = {};
    a[0] = (_Float16)(f6[0] * C3);
    a[1] = (_Float16)(f6[1] * C3);
    a[2] = (_Float16)(f6[2] * C3);
    a[6] = (_Float16)(-h3 * C3);
    a[7] = (_Float16)1.0f;
    ajs8[n] = a;
    half8 b;
#pragma unroll
    for (int d = 0; d < 6; ++d) b[d] = (_Float16)(f6[d] * LOG2E);
    b[6] = (_Float16)(-h6v * LOG2E);
    b[7] = (_Float16)1.0f;
    ajb8[n] = b;

    float q[C];
#pragma unroll
    for (int c = 0; c < C; ++c) q[c] = unaries[c * N + n];
    float m = q[0];
#pragma unroll
    for (int c = 1; c < C; ++c) m = fmaxf(m, q[c]);
    float e[C], s = 0.0f;
#pragma unroll
    for (int c = 0; c < C; ++c) {
        e[c] = __builtin_amdgcn_exp2f((q[c] - m) * LOG2E);
        s += e[c];
    }
    float inv = 1.0f / s;
#pragma unroll
    for (int c = 0; c < C; ++c) pf0[c * N + n] = (_Float16)(e[c] * inv);
#pragma unroll
    for (int c = C; c < 16; ++c) {
        pf0[c * N + n] = (_Float16)0.0f;
        pf1[c * N + n] = (_Float16)0.0f;
    }
}

// one dispatch per CRF iteration: block owns 32 i's; 16 waves sweep all N j's
// (wave w takes 64 j's of each 1024-j window); double-buffered LDS windows
// (1 barrier per window); LDS-reduce across waves; combine + softmax in-block.
__global__ __launch_bounds__(FBLOCK, 4) void fused_kernel(
    const float* __restrict__ unaries, const float* __restrict__ feat,
    const float* __restrict__ SW, const float* __restrict__ BW,
    const float* __restrict__ CM,
    const float4* __restrict__ ajsv, const float4* __restrict__ ajbv,
    const _Float16* __restrict__ pf_in, _Float16* __restrict__ pf_out,
    float* __restrict__ out, int is_last) {
    __shared__ FusedSmem sm;
    int t = threadIdx.x;
    int i0 = blockIdx.x * IBLK;
    int lane = t & 63;
    int w = t >> 6;            // wave id 0..15
    int il = lane & 15;
    int quad = lane >> 4;
    int h = quad & 1;
    bool klo = (quad < 2);
    const half4 hz = {};

    // ---- i-side B1 fragments (32 i's, 2 subtiles of 16) ----
    half4 b1s0, b1s1, b1b0, b1b1;
#pragma unroll
    for (int s = 0; s < 2; ++s) {
        int i = i0 + s * 16 + il;
        float g0 = feat[0 * N + i], g1 = feat[1 * N + i], g2 = feat[2 * N + i];
        float g3 = feat[3 * N + i], g4 = feat[4 * N + i], g5 = feat[5 * N + i];
        float h3 = 0.5f * (g0 * g0 + g1 * g1 + g2 * g2);
        float h6v = h3 + 0.5f * (g3 * g3 + g4 * g4 + g5 * g5);
        half4 slo = {(_Float16)g0, (_Float16)g1, (_Float16)g2, (_Float16)0.0f};
        half4 shi = {(_Float16)0.0f, (_Float16)0.0f, (_Float16)1.0f, (_Float16)(-h3 * C3)};
        half4 blo = {(_Float16)g0, (_Float16)g1, (_Float16)g2, (_Float16)g3};
        half4 bhi = {(_Float16)g4, (_Float16)g5, (_Float16)1.0f, (_Float16)(-h6v * LOG2E)};
        half4 vs = klo ? (h ? shi : slo) : hz;
        half4 vb = klo ? (h ? bhi : blo) : hz;
        if (s == 0) { b1s0 = vs; b1b0 = vb; } else { b1s1 = vs; b1b1 = vb; }
    }

    f32x4 as0 = {0.f, 0.f, 0.f, 0.f}, as1 = {0.f, 0.f, 0.f, 0.f};
    f32x4 ab0 = {0.f, 0.f, 0.f, 0.f}, ab1 = {0.f, 0.f, 0.f, 0.f};
    const f32x4 zero = {0.f, 0.f, 0.f, 0.f};

    const float4* ps = (const float4*)pf_in;
    int c0 = t >> 6, o0 = t & 63;            // p-staging: row c0 (0..15), offsets o0, o0+64

    // ---- prologue: win0 -> buf0; issue win1 loads ----
    float4 r_s = ajsv[t];
    float4 r_b = ajbv[t];
    float4 r_p0 = ps[c0 * (N / 8) + o0];
    float4 r_p1 = ps[c0 * (N / 8) + 64 + o0];
    stage_write(&sm.f[0], t, c0, o0, r_s, r_b, r_p0, r_p1);
    r_s = ajsv[JT + t];
    r_b = ajbv[JT + t];
    r_p0 = ps[c0 * (N / 8) + 128 + o0];
    r_p1 = ps[c0 * (N / 8) + 192 + o0];
    __syncthreads();

    for (int win = 0; win < NWIN; ++win) {
        FilterSmem* fb = &sm.f[win & 1];
        // compute: wave w handles j in [w*64, w*64+64) of this window
#pragma unroll
        for (int s = 0; s < 2; ++s) {
            int jb = w * 64 + s * 32;
            int j0 = jb, j1 = jb + 16;
            half4 vs0 = fb->ajs_l[(j0 + il) * 2 + h];
            half4 vb0 = fb->ajb_l[(j0 + il) * 2 + h];
            half4 vs1 = fb->ajs_l[(j1 + il) * 2 + h];
            half4 vb1 = fb->ajb_l[(j1 + il) * 2 + h];
            half4 p2_0 = *(const half4*)&fb->p_l[il * PROW + j0 + quad * 4];
            half4 p2_1 = *(const half4*)&fb->p_l[il * PROW + j1 + quad * 4];
            half4 a1s_0 = klo ? vs0 : hz;
            half4 a1b_0 = klo ? vb0 : hz;
            half4 a1s_1 = klo ? vs1 : hz;
            half4 a1b_1 = klo ? vb1 : hz;

            // GEMM-1: S^T[j][i] in C/D layout (8 independent chains)
            f32x4 d0 = __builtin_amdgcn_mfma_f32_16x16x16f16(a1s_0, b1s0, zero, 0, 0, 0);
            f32x4 d1 = __builtin_amdgcn_mfma_f32_16x16x16f16(a1s_0, b1s1, zero, 0, 0, 0);
            f32x4 d2 = __builtin_amdgcn_mfma_f32_16x16x16f16(a1b_0, b1b0, zero, 0, 0, 0);
            f32x4 d3 = __builtin_amdgcn_mfma_f32_16x16x16f16(a1b_0, b1b1, zero, 0, 0, 0);
            f32x4 d4 = __builtin_amdgcn_mfma_f32_16x16x16f16(a1s_1, b1s0, zero, 0, 0, 0);
            f32x4 d5 = __builtin_amdgcn_mfma_f32_16x16x16f16(a1s_1, b1s1, zero, 0, 0, 0);
            f32x4 d6 = __builtin_amdgcn_mfma_f32_16x16x16f16(a1b_1, b1b0, zero, 0, 0, 0);
            f32x4 d7 = __builtin_amdgcn_mfma_f32_16x16x16f16(a1b_1, b1b1, zero, 0, 0, 0);

            half4 w0 = expcvt(d0), w1 = expcvt(d1), w2 = expcvt(d2), w3 = expcvt(d3);
            half4 w4 = expcvt(d4), w5 = expcvt(d5), w6 = expcvt(d6), w7 = expcvt(d7);

            // GEMM-2: out[i][c] += w[i][j] * p[c][j]
            as0 = __builtin_amdgcn_mfma_f32_16x16x16f16(w0, p2_0, as0, 0, 0, 0);
            as1 = __builtin_amdgcn_mfma_f32_16x16x16f16(w1, p2_0, as1, 0, 0, 0);
            ab0 = __builtin_amdgcn_mfma_f32_16x16x16f16(w2, p2_0, ab0, 0, 0, 0);
            ab1 = __builtin_amdgcn_mfma_f32_16x16x16f16(w3, p2_0, ab1, 0, 0, 0);
            as0 = __builtin_amdgcn_mfma_f32_16x16x16f16(w4, p2_1, as0, 0, 0, 0);
            as1 = __builtin_amdgcn_mfma_f32_16x16x16f16(w5, p2_1, as1, 0, 0, 0);
            ab0 = __builtin_amdgcn_mfma_f32_16x16x16f16(w6, p2_1, ab0, 0, 0, 0);
            ab1 = __builtin_amdgcn_mfma_f32_16x16x16f16(w7, p2_1, ab1, 0, 0, 0);
        }
        // stage next window into the other buffer (no barrier needed before:
        // fast waves write buf[win+1] while slow waves still read buf[win])
        if (win + 1 < NWIN) {
            stage_write(&sm.f[(win + 1) & 1], t, c0, o0, r_s, r_b, r_p0, r_p1);
            if (win + 2 < NWIN) {
                int jb2 = (win + 2) * JT;
                r_s = ajsv[jb2 + t];
                r_b = ajbv[jb2 + t];
                r_p0 = ps[c0 * (N / 8) + (jb2 >> 3) + o0];
                r_p1 = ps[c0 * (N / 8) + (jb2 >> 3) + 64 + o0];
            }
        }
        __syncthreads();
    }

    // ---- cross-wave reduction in LDS (conflict-free dump: r*64+lane) ----
    {
        float* rb = sm.rbuf + w * 1024;
#pragma unroll
        for (int r = 0; r < 4; ++r) {
            rb[r * 64 + lane]       = as0[r];
            rb[256 + r * 64 + lane] = as1[r];
            rb[512 + r * 64 + lane] = ab0[r];
            rb[768 + r * 64 + lane] = ab1[r];
        }
    }
    __syncthreads();
    {
        float tot = 0.f;
#pragma unroll
        for (int w2 = 0; w2 < 16; ++w2) tot += sm.rbuf[w2 * 1024 + t];
        // in-place: position t is only ever read by thread t (w2=0 term)
        sm.rbuf[t] = tot;
    }
    __syncthreads();

    // ---- combine + compatibility + softmax for this block's 32 i's ----
    if (t < IBLK) {
        int i = i0 + t;
        int sub = t >> 4, ql = (t & 15) >> 2, rr = t & 3;
        float sp[C], bl[C];
#pragma unroll
        for (int c = 0; c < C; ++c) {
            int base = sub * 256 + rr * 64 + ql * 16 + c;
            sp[c] = sm.rbuf[base];
            bl[c] = sm.rbuf[base + 512];
        }
        float msg[C];
#pragma unroll
        for (int c = 0; c < C; ++c) {
            float m = 0.f;
#pragma unroll
            for (int k = 0; k < C; ++k)
                m += SW[c * C + k] * sp[k] + BW[c * C + k] * bl[k];
            msg[c] = m;
        }
        float qq[C];
#pragma unroll
        for (int c = 0; c < C; ++c) {
            float pw = 0.f;
#pragma unroll
            for (int k = 0; k < C; ++k) pw += CM[c * C + k] * msg[k];
            qq[c] = unaries[c * N + i] - pw;
        }
        if (is_last) {
#pragma unroll
            for (int c = 0; c < C; ++c) out[c * N + i] = qq[c];
        } else {
            float m = qq[0];
#pragma unroll
            for (int c = 1; c < C; ++c) m = fmaxf(m, qq[c]);
            float e[C], s = 0.0f;
#pragma unroll
            for (int c = 0; c < C; ++c) {
                e[c] = __builtin_amdgcn_exp2f((qq[c] - m) * LOG2E);
                s += e[c];
            }
            float inv = 1.0f / s;
#pragma unroll
            for (int c = 0; c < C; ++c) pf_out[c * N + i] = (_Float16)(e[c] * inv);
        }
    }
}

extern "C" void kernel_launch(void* const* d_in, const int* in_sizes, int n_in,
                              void* d_out, int out_size, void* d_ws, size_t ws_size,
                              hipStream_t stream) {
    const float* unaries = (const float*)d_in[0];   // [10, 8192]
    const float* feat    = (const float*)d_in[1];   // [6, 8192]
    const float* SW      = (const float*)d_in[2];   // [10,10]
    const float* BW      = (const float*)d_in[3];   // [10,10]
    const float* CM      = (const float*)d_in[4];   // [10,10]
    float* out = (float*)d_out;

    char* ws = (char*)d_ws;
    half8* ajs    = (half8*)(ws + WS_AJS);
    half8* ajb    = (half8*)(ws + WS_AJB);
    _Float16* pf0 = (_Float16*)(ws + WS_PF0);
    _Float16* pf1 = (_Float16*)(ws + WS_PF1);

    init_kernel<<<N / 256, 256, 0, stream>>>(unaries, feat, ajs, ajb, pf0, pf1);
    const _Float16* pin = pf0;
    _Float16* pout = pf1;
    for (int it = 1; it <= NUM_ITERS; ++it) {
        fused_kernel<<<NBLK, FBLOCK, 0, stream>>>(
            unaries, feat, SW, BW, CM, (const float4*)ajs, (const float4*)ajb,
            pin, pout, out, it == NUM_ITERS ? 1 : 0);
        const _Float16* tmp = pout;
        pout = (_Float16*)pin;
        pin = tmp;
    }
}